// Round 14
// baseline (478.722 us; speedup 1.0000x reference)
//
#include <hip/hip_runtime.h>
#include <hip/hip_bf16.h>

#define SS 2048
#define BB 16
#define DD 512

typedef __attribute__((ext_vector_type(4))) float f32x4;
typedef __attribute__((ext_vector_type(8))) short bf16x8;
typedef __attribute__((ext_vector_type(4))) unsigned short us4;
typedef unsigned short us;

#define MFMA16(a,b,c) __builtin_amdgcn_mfma_f32_16x16x32_bf16((a),(b),(c),0,0,0)
#define BAR() __builtin_amdgcn_s_barrier()
#define WAITV(n) asm volatile("s_waitcnt vmcnt(" #n ")" ::: "memory")
#define WAITL()  asm volatile("s_waitcnt lgkmcnt(0)" ::: "memory")

__device__ __forceinline__ unsigned short f2b(float f) {
    union { float f; unsigned u; } v; v.f = f;
    unsigned r = v.u + 0x7FFFu + ((v.u >> 16) & 1u);
    return (unsigned short)(r >> 16);
}

// 256B-row LDS tile, 4-bit XOR swizzle (16-slot spread)
__device__ __forceinline__ bf16x8 ldfrag8(const us* base, int row, int kelem) {
    int off = (row << 8) + (kelem << 1);
    off ^= (row & 15) << 4;
    return *(const bf16x8*)((const char*)base + off);
}
// 128B-row (k_gemm)
__device__ __forceinline__ bf16x8 ldfrag(const us* base, int row, int kelem, int rowshift) {
    int off = (row << rowshift) + (kelem << 1);
    off ^= (row & 7) << 4;
    return *(const bf16x8*)((const char*)base + off);
}

__device__ __forceinline__ void gl16(const void* g, void* l) {
    __builtin_amdgcn_global_load_lds(
        (const __attribute__((address_space(1))) unsigned*)g,
        (__attribute__((address_space(3))) unsigned*)l, 16, 0, 0);
}

// ---------------------------------------------------------------------------
// Prep: seq [S][B][D] fp32 -> Xb [B][S][D] bf16 and Xbt [B][D][S] bf16.
// ---------------------------------------------------------------------------
__global__ __launch_bounds__(256) void k_prep_x(const float* __restrict__ seq,
        us* __restrict__ Xb, us* __restrict__ Xbt) {
    __shared__ __align__(16) char L[64 * 128];
    const int tid = threadIdx.x;
    const int d0 = blockIdx.x * 64, s0 = blockIdx.y * 64, b = blockIdx.z;
    {
        int r = tid >> 2, seg = (tid & 3) * 16;
        const float* src = seq + (size_t)(s0 + r) * (BB * DD) + (size_t)b * DD + d0 + seg;
        __align__(16) us vals[16];
        #pragma unroll
        for (int q = 0; q < 4; ++q) {
            f32x4 v = *(const f32x4*)(src + q * 4);
            vals[q*4+0] = f2b(v.x); vals[q*4+1] = f2b(v.y);
            vals[q*4+2] = f2b(v.z); vals[q*4+3] = f2b(v.w);
        }
        us* xo = Xb + ((size_t)b * SS + s0 + r) * DD + d0 + seg;
        *(bf16x8*)xo       = *(bf16x8*)&vals[0];
        *(bf16x8*)(xo + 8) = *(bf16x8*)&vals[8];
        #pragma unroll
        for (int j = 0; j < 16; ++j) {
            int d = seg + j;
            int addr = (d * 128 + r * 2) ^ ((d & 7) << 4);
            *(us*)(L + addr) = vals[j];
        }
    }
    __syncthreads();
    {
        int d = tid >> 2, sseg = (tid & 3) * 16;
        int c = (d & 7) << 4;
        int base = d * 128 + sseg * 2;
        bf16x8 h0 = *(bf16x8*)(L + (base ^ c));
        bf16x8 h1 = *(bf16x8*)(L + ((base + 16) ^ c));
        us* o = Xbt + ((size_t)b * DD + d0 + d) * SS + s0 + sseg;
        *(bf16x8*)o       = h0;
        *(bf16x8*)(o + 8) = h1;
    }
}

// ---------------------------------------------------------------------------
// Gt[p][i] = (1/sqrt(D)) * sum_a Wv[a,i] * Wq[a,p]
// ---------------------------------------------------------------------------
__global__ __launch_bounds__(256) void k_prepG(const float* __restrict__ Wv,
        const float* __restrict__ Wq, us* __restrict__ Gt) {
    __shared__ float Sq[32][64], Sv[32][64];
    const int tid = threadIdx.x;
    const int p0 = blockIdx.x * 64, i0 = blockIdx.y * 64;
    const int tp = tid & 15, ti = tid >> 4;
    float acc[4][4] = {};
    for (int a0 = 0; a0 < DD; a0 += 32) {
        #pragma unroll
        for (int j = 0; j < 2; ++j) {
            int slot = tid + j * 256;
            int row = slot >> 4, c4 = (slot & 15) * 4;
            *(f32x4*)&Sq[row][c4] = *(const f32x4*)(Wq + (size_t)(a0 + row) * DD + p0 + c4);
            *(f32x4*)&Sv[row][c4] = *(const f32x4*)(Wv + (size_t)(a0 + row) * DD + i0 + c4);
        }
        __syncthreads();
        for (int a = 0; a < 32; ++a) {
            f32x4 q = *(f32x4*)&Sq[a][tp * 4];
            f32x4 v = *(f32x4*)&Sv[a][ti * 4];
            #pragma unroll
            for (int x = 0; x < 4; ++x)
                #pragma unroll
                for (int y = 0; y < 4; ++y)
                    acc[x][y] += q[x] * v[y];
        }
        __syncthreads();
    }
    const float sc = 0.044194173824159216f;
    #pragma unroll
    for (int x = 0; x < 4; ++x)
        #pragma unroll
        for (int y = 0; y < 4; ++y)
            Gt[(size_t)(p0 + tp * 4 + x) * DD + i0 + ti * 4 + y] = f2b(acc[x][y] * sc);
}

// u[p] = (1/sqrt(D)) * sum_a bv[a] * Wq[a,p]
__global__ __launch_bounds__(512) void k_prepU(const float* __restrict__ Wq,
        const float* __restrict__ bv, float* __restrict__ u) {
    int p = threadIdx.x;
    float s = 0.f;
    for (int a0 = 0; a0 < DD; a0 += 8) {
        #pragma unroll
        for (int j = 0; j < 8; ++j)
            s += bv[a0 + j] * Wq[(size_t)(a0 + j) * DD + p];
    }
    u[p] = s * 0.044194173824159216f;
}

__global__ void k_prepW(const float* __restrict__ Wk, us* __restrict__ Wkb) {
    int i = (blockIdx.x * 256 + threadIdx.x) * 4;
    f32x4 v = *(const f32x4*)(Wk + i);
    us4 o; o.x = f2b(v.x); o.y = f2b(v.y); o.z = f2b(v.z); o.w = f2b(v.w);
    *(us4*)(Wkb + i) = o;
}

// ---------------------------------------------------------------------------
// bf16 GEMM: C[row,n] = sum_k A[row,k]*Bm[n,k] + bias[n]
// ---------------------------------------------------------------------------
template<int OUTMODE>
__global__ __launch_bounds__(256, 2) void k_gemm(
        const us* __restrict__ A, const us* __restrict__ Bm,
        const float* __restrict__ bias, void* __restrict__ outp) {
    __shared__ __align__(16) us As[2][128 * 64];
    __shared__ __align__(16) us Bs[2][128 * 64];
    const int tid = threadIdx.x;
    const int lane = tid & 63;
    const int w = tid >> 6;
    const int wr = w >> 1, wc = w & 1;
    const int l15 = lane & 15, lg = lane >> 4;
    const int b = blockIdx.x >> 4;
    const int s0 = (blockIdx.x & 15) * 128;
    const int n0 = blockIdx.y * 128;
    const char* abase = (const char*)(A + ((size_t)b * SS + s0) * DD);
    const char* bbase = (const char*)Bm + (size_t)n0 * 1024;

    f32x4 acc[4][4];
    #pragma unroll
    for (int m = 0; m < 4; ++m)
        #pragma unroll
        for (int n = 0; n < 4; ++n) acc[m][n] = (f32x4)(0.0f);

    auto stage = [&](int db, int p) {
        #pragma unroll
        for (int j = 0; j < 4; ++j) {
            int x = (tid + j * 256) * 16;
            int gx = x ^ (((x >> 7) & 7) << 4);
            int row = gx >> 7, col = gx & 127;
            gl16(abase + (size_t)row * 1024 + p * 128 + col, (char*)As[db] + x);
            gl16(bbase + (size_t)row * 1024 + p * 128 + col, (char*)Bs[db] + x);
        }
    };

    stage(0, 0);
    for (int p = 0; p < 8; ++p) {
        if (p < 7) { stage((p + 1) & 1, p + 1); WAITV(8); }
        else       { WAITV(0); }
        BAR();
        const us* Ac = As[p & 1]; const us* Bc = Bs[p & 1];
        __builtin_amdgcn_s_setprio(1);
        #pragma unroll
        for (int kk = 0; kk < 2; ++kk) {
            bf16x8 af[4], bfr[4];
            #pragma unroll
            for (int m = 0; m < 4; ++m) af[m]  = ldfrag(Ac, 64 * wr + 16 * m + l15, kk * 32 + 8 * lg, 7);
            #pragma unroll
            for (int n = 0; n < 4; ++n) bfr[n] = ldfrag(Bc, 64 * wc + 16 * n + l15, kk * 32 + 8 * lg, 7);
            #pragma unroll
            for (int m = 0; m < 4; ++m)
                #pragma unroll
                for (int n = 0; n < 4; ++n)
                    acc[m][n] = MFMA16(af[m], bfr[n], acc[m][n]);
        }
        __builtin_amdgcn_s_setprio(0);
        BAR();
    }

    #pragma unroll
    for (int m = 0; m < 4; ++m) {
        #pragma unroll
        for (int n = 0; n < 4; ++n) {
            int col = n0 + 64 * wc + 16 * n + l15;
            float bia = bias[col];
            #pragma unroll
            for (int r = 0; r < 4; ++r) {
                int row = s0 + 64 * wr + 16 * m + 4 * lg + r;
                float v = acc[m][n][r] + bia;
                if (OUTMODE == 0)
                    ((us*)outp)[((size_t)b * SS + row) * DD + col] = f2b(v);
                else
                    ((float*)outp)[((size_t)row * BB + b) * DD + col] = v;
            }
        }
    }
}

// ---------------------------------------------------------------------------
// Flash attention v17 = r11 + MERGED INTERVALS: with static-max softmax,
//   QK(n+1) is independent of PV(n) -> each barrier interval executes
//   QK-phase-p(n+1) AND PV-phase-p(n): 32 MFMA + 32 reads per wave per
//   interval, HALVING interval count (144 -> 68) at identical traffic,
//   registers (+16 for sacc/pa co-live), and LDS.
//   Chunk stream: X0(n+1), XT0(n), X1(n+1), XT1(n), ... through ring-4 FIFO;
//   each interval consumes the 2 oldest (WAITV(8), 2-interval lookahead),
//   reissues 2.  Prologue = standalone QK(0); step 15's QK reads wrapped
//   dummy chunks (discarded).  Geometry/locality/registers = r11 verbatim.
// ---------------------------------------------------------------------------
__global__ __launch_bounds__(512, 2) void k_attn(
        const us* __restrict__ Vtb, const us* __restrict__ Xb,
        const us* __restrict__ Xbt, us* __restrict__ Ob) {
    __shared__ __align__(16) us BUFS[4][16384];  // 4 x 32KB ring
    __shared__ __align__(16) us Pb[64 * 128];    // P [64 r][128 t], 256B rows, swz
    __shared__ float red[2][64];

    const int tid = threadIdx.x;
    const int lane = tid & 63;
    const int w = tid >> 6;
    const int rg = w & 3;          // rows 16*rg .. +15
    const int cg = w >> 2;         // t-half (QK) / e-half-within-quarter (PV)
    const int l15 = lane & 15, lg = lane >> 4;

    // XCD-batch locality (r11): XCD x = wg&7 -> batch 8*(wg>>8)+x
    const int wg = blockIdx.x;
    const int b  = ((wg >> 8) << 3) | (wg & 7);
    const int s0 = ((wg >> 3) & 31) * 64;

    const char* vbase  = (const char*)(Vtb + ((size_t)b * SS + s0) * DD);
    const char* xabase = (const char*)(Xb  + (size_t)b * SS * DD);
    const char* xtbase = (const char*)(Xbt + (size_t)b * DD * SS);

    // chunk flat c: i=c&7: i<4 -> X k-quarter i rows t0..t0+127;
    //               i>=4 -> XT e-quarter (i-4) cols t0..t0+127;  t0=(c>>3)*128
    auto issue = [&](int cflat, us* dst0) {
        int c = cflat & 127;
        int i = c & 7, t0 = (c >> 3) << 7;
        char* dst = (char*)dst0;
        if (i < 4) {
            #pragma unroll
            for (int j = 0; j < 4; ++j) {
                int x = tid * 16 + j * 8192;
                int gx = x ^ (((x >> 8) & 15) << 4);
                int row = gx >> 8, col = gx & 255;
                gl16(xabase + (size_t)(t0 + row) * 1024 + i * 256 + col, dst + x);
            }
        } else {
            #pragma unroll
            for (int j = 0; j < 4; ++j) {
                int x = tid * 16 + j * 8192;
                int gx = x ^ (((x >> 8) & 15) << 4);
                int row = gx >> 8, col = gx & 255;
                gl16(xtbase + (size_t)((i - 4) * 128 + row) * (SS * 2)
                            + (size_t)t0 * 2 + col, dst + x);
            }
        }
    };

    // ---- prologue: Vt tile (64 rows x 512 k) -> af regs via 4x16KB subs ----
    #pragma unroll
    for (int p = 0; p < 4; ++p) {
        #pragma unroll
        for (int j = 0; j < 2; ++j) {
            int x = tid * 16 + j * 8192;
            int gx = x ^ (((x >> 8) & 15) << 4);
            int row = gx >> 8, col = gx & 255;
            gl16(vbase + (size_t)row * 1024 + p * 256 + col,
                 (char*)BUFS[0] + p * 16384 + x);
        }
    }
    WAITV(0); BAR();
    bf16x8 af[16];
    #pragma unroll
    for (int p = 0; p < 4; ++p)
        #pragma unroll
        for (int kk = 0; kk < 4; ++kk)
            af[4 * p + kk] = ldfrag8((const us*)BUFS[0] + p * 8192,
                                     16 * rg + l15, 32 * kk + 8 * lg);
    WAITL(); BAR();

    f32x4 accv[4][4];
    #pragma unroll
    for (int ph = 0; ph < 4; ++ph)
        #pragma unroll
        for (int nt = 0; nt < 4; ++nt) accv[ph][nt] = (f32x4)(0.0f);
    float lsum[4] = {0.f, 0.f, 0.f, 0.f};
    const int idx = 16 * rg + 4 * lg;

    f32x4 sacc[4];
    #pragma unroll
    for (int nt = 0; nt < 4; ++nt) sacc[nt] = (f32x4)(0.0f);
    bf16x8 pa[4];

    // softmax: sacc -> exp -> Pb -> pa; accumulate lsum (per-step rowsums)
    auto softmax = [&]() {
        #pragma unroll
        for (int nt = 0; nt < 4; ++nt)
            #pragma unroll
            for (int ri = 0; ri < 4; ++ri)
                sacc[nt][ri] = __expf(sacc[nt][ri]);
        #pragma unroll
        for (int nt = 0; nt < 4; ++nt)
            #pragma unroll
            for (int ri = 0; ri < 4; ++ri) {
                int row = idx + ri;
                int col = 64 * cg + 16 * nt + l15;
                int off = ((row << 8) + (col << 1)) ^ ((row & 15) << 4);
                *(us*)((char*)Pb + off) = f2b(sacc[nt][ri]);
            }
        #pragma unroll
        for (int ri = 0; ri < 4; ++ri) {
            float s = sacc[0][ri] + sacc[1][ri] + sacc[2][ri] + sacc[3][ri];
            s += __shfl_xor(s, 1); s += __shfl_xor(s, 2);
            s += __shfl_xor(s, 4); s += __shfl_xor(s, 8);
            lsum[ri] += s;
        }
        WAITL(); BAR();
        #pragma unroll
        for (int kk = 0; kk < 4; ++kk)
            pa[kk] = ldfrag8(Pb, 16 * rg + l15, 32 * kk + 8 * lg);
        #pragma unroll
        for (int nt = 0; nt < 4; ++nt) sacc[nt] = (f32x4)(0.0f);
    };

    // ---- bootstrap: issue QK(0) chunks, run standalone QK(0) ----
    issue(0, BUFS[0]); issue(1, BUFS[1]); issue(2, BUFS[2]); issue(3, BUFS[3]);
    #pragma unroll
    for (int p = 0; p < 4; ++p) {
        WAITV(12); BAR();
        const us* sl = BUFS[p];
        __builtin_amdgcn_s_setprio(1);
        #pragma unroll
        for (int kk = 0; kk < 4; ++kk)
            #pragma unroll
            for (int nt = 0; nt < 4; ++nt) {
                bf16x8 bq = ldfrag8(sl, 64 * cg + 16 * nt + l15, 32 * kk + 8 * lg);
                sacc[nt] = MFMA16(af[4 * p + kk], bq, sacc[nt]);
            }
        __builtin_amdgcn_s_setprio(0);
        BAR();
        // main-stream entries 0..3: e even -> X_{e/2}(1), e odd -> XT_{e/2}(0)
        if (p == 0) issue(8 + 0, BUFS[0]);       // X0(1)
        if (p == 1) issue(0 + 4 + 0, BUFS[1]);   // XT0(0)
        if (p == 2) issue(8 + 1, BUFS[2]);       // X1(1)
        if (p == 3) issue(0 + 4 + 1, BUFS[3]);   // XT1(0)
    }
    softmax();   // P(0) -> pa(0)

    // ---- main loop: 16 steps x 4 merged intervals ----
    for (int n = 0; n < 16; ++n) {
        #pragma unroll
        for (int p = 0; p < 4; ++p) {
            const int m = n * 4 + p;
            const int sA = (m & 1) * 2, sB = sA + 1;
            WAITV(8); BAR();
            const us* slA = BUFS[sA];   // X_p(n+1)
            const us* slB = BUFS[sB];   // XT_p(n)
            __builtin_amdgcn_s_setprio(1);
            #pragma unroll
            for (int kk = 0; kk < 4; ++kk)
                #pragma unroll
                for (int nt = 0; nt < 4; ++nt) {
                    bf16x8 bq = ldfrag8(slA, 64 * cg + 16 * nt + l15, 32 * kk + 8 * lg);
                    sacc[nt] = MFMA16(af[4 * p + kk], bq, sacc[nt]);
                }
            #pragma unroll
            for (int kk = 0; kk < 4; ++kk)
                #pragma unroll
                for (int nt = 0; nt < 4; ++nt) {
                    bf16x8 bx = ldfrag8(slB, 64 * cg + 16 * nt + l15, 32 * kk + 8 * lg);
                    accv[p][nt] = MFMA16(pa[kk], bx, accv[p][nt]);
                }
            __builtin_amdgcn_s_setprio(0);
            BAR();
            // issue entries 2 intervals ahead: q = m+2 -> step n'=q>>2, phase p'=q&3
            const int q = m + 2;
            const int np = q >> 2, pp = q & 3;
            issue(((np + 1) & 15) * 8 + pp, BUFS[sA]);       // X_pp(np+1)
            issue((np & 15) * 8 + 4 + pp, BUFS[sB]);          // XT_pp(np)
        }
        if (n < 15) softmax();   // P(n+1) -> pa(n+1)
    }

    WAITV(0);
    // ---- epilogue: cross-cg lsum exchange, O' = accv / tot ----
    if (l15 == 0) {
        #pragma unroll
        for (int ri = 0; ri < 4; ++ri)
            red[cg][idx + ri] = lsum[ri];
    }
    WAITL(); BAR();
    float tot[4];
    #pragma unroll
    for (int ri = 0; ri < 4; ++ri)
        tot[ri] = red[0][idx + ri] + red[1][idx + ri];
    us* orow = Ob + ((size_t)b * SS + s0) * DD;
    #pragma unroll
    for (int ph = 0; ph < 4; ++ph)
        #pragma unroll
        for (int nt = 0; nt < 4; ++nt)
            #pragma unroll
            for (int ri = 0; ri < 4; ++ri) {
                int row = idx + ri;
                int e = 128 * ph + 64 * cg + 16 * nt + l15;
                orow[(size_t)row * DD + e] = f2b(accv[ph][nt][ri] / tot[ri]);
            }
}

extern "C" void kernel_launch(void* const* d_in, const int* in_sizes, int n_in,
                              void* d_out, int out_size, void* d_ws, size_t ws_size,
                              hipStream_t stream) {
    const float* seq = (const float*)d_in[0];
    const float* Wv  = (const float*)d_in[1];
    const float* bv  = (const float*)d_in[2];
    const float* Wq  = (const float*)d_in[3];
    // d_in[4] = bq: softmax-row-constant -> unused
    const float* Wk  = (const float*)d_in[5];
    const float* bk  = (const float*)d_in[6];

    char* ws = (char*)d_ws;
    us*    Xb  = (us*)ws;                                  // [B][S][D] bf16, 32MB
    us*    Xbt = (us*)(ws + (size_t)33554432);             // [B][D][S] bf16, 32MB
    us*    Vtb = (us*)(ws + (size_t)67108864);             // [B][S][D] bf16, 32MB (reused as O')
    us*    Gt  = (us*)(ws + (size_t)100663296);            // [D][D] bf16
    us*    Wkb = (us*)(ws + (size_t)101187584);            // [D][D] bf16
    float* u   = (float*)(ws + (size_t)101711872);         // [D] fp32

    k_prep_x<<<dim3(8, 32, 16), 256, 0, stream>>>(seq, Xb, Xbt);
    k_prepG<<<dim3(8, 8), 256, 0, stream>>>(Wv, Wq, Gt);
    k_prepU<<<1, 512, 0, stream>>>(Wq, bv, u);
    k_prepW<<<256, 256, 0, stream>>>(Wk, Wkb);

    k_gemm<0><<<dim3(256, 4), 256, 0, stream>>>(Xb, Gt, u, (void*)Vtb);   // Vt = X*G + u
    k_attn<<<512, 512, 0, stream>>>(Vtb, Xb, Xbt, Vtb);                   // O' over Vt
    k_gemm<1><<<dim3(256, 4), 256, 0, stream>>>(Vtb, Wkb, bk, d_out);     // out = O'*Wk^T + bk
}

// Round 15
// 350.491 us; speedup vs baseline: 1.3659x; 1.3659x over previous
//
#include <hip/hip_runtime.h>
#include <hip/hip_bf16.h>

#define SS 2048
#define BB 16
#define DD 512

typedef __attribute__((ext_vector_type(4))) float f32x4;
typedef __attribute__((ext_vector_type(8))) short bf16x8;
typedef __attribute__((ext_vector_type(4))) unsigned short us4;
typedef unsigned short us;

#define MFMA16(a,b,c) __builtin_amdgcn_mfma_f32_16x16x32_bf16((a),(b),(c),0,0,0)
#define BAR() __builtin_amdgcn_s_barrier()
#define WAITV(n) asm volatile("s_waitcnt vmcnt(" #n ")" ::: "memory")
#define WAITL()  asm volatile("s_waitcnt lgkmcnt(0)" ::: "memory")

__device__ __forceinline__ unsigned short f2b(float f) {
    union { float f; unsigned u; } v; v.f = f;
    unsigned r = v.u + 0x7FFFu + ((v.u >> 16) & 1u);
    return (unsigned short)(r >> 16);
}

// 256B-row LDS tile, 4-bit XOR swizzle (16-slot spread)
__device__ __forceinline__ bf16x8 ldfrag8(const us* base, int row, int kelem) {
    int off = (row << 8) + (kelem << 1);
    off ^= (row & 15) << 4;
    return *(const bf16x8*)((const char*)base + off);
}
// 128B-row (k_gemm)
__device__ __forceinline__ bf16x8 ldfrag(const us* base, int row, int kelem, int rowshift) {
    int off = (row << rowshift) + (kelem << 1);
    off ^= (row & 7) << 4;
    return *(const bf16x8*)((const char*)base + off);
}

__device__ __forceinline__ void gl16(const void* g, void* l) {
    __builtin_amdgcn_global_load_lds(
        (const __attribute__((address_space(1))) unsigned*)g,
        (__attribute__((address_space(3))) unsigned*)l, 16, 0, 0);
}

// ---------------------------------------------------------------------------
// Prep: seq [S][B][D] fp32 -> Xb [B][S][D] bf16 and Xbt [B][D][S] bf16.
// ---------------------------------------------------------------------------
__global__ __launch_bounds__(256) void k_prep_x(const float* __restrict__ seq,
        us* __restrict__ Xb, us* __restrict__ Xbt) {
    __shared__ __align__(16) char L[64 * 128];
    const int tid = threadIdx.x;
    const int d0 = blockIdx.x * 64, s0 = blockIdx.y * 64, b = blockIdx.z;
    {
        int r = tid >> 2, seg = (tid & 3) * 16;
        const float* src = seq + (size_t)(s0 + r) * (BB * DD) + (size_t)b * DD + d0 + seg;
        __align__(16) us vals[16];
        #pragma unroll
        for (int q = 0; q < 4; ++q) {
            f32x4 v = *(const f32x4*)(src + q * 4);
            vals[q*4+0] = f2b(v.x); vals[q*4+1] = f2b(v.y);
            vals[q*4+2] = f2b(v.z); vals[q*4+3] = f2b(v.w);
        }
        us* xo = Xb + ((size_t)b * SS + s0 + r) * DD + d0 + seg;
        *(bf16x8*)xo       = *(bf16x8*)&vals[0];
        *(bf16x8*)(xo + 8) = *(bf16x8*)&vals[8];
        #pragma unroll
        for (int j = 0; j < 16; ++j) {
            int d = seg + j;
            int addr = (d * 128 + r * 2) ^ ((d & 7) << 4);
            *(us*)(L + addr) = vals[j];
        }
    }
    __syncthreads();
    {
        int d = tid >> 2, sseg = (tid & 3) * 16;
        int c = (d & 7) << 4;
        int base = d * 128 + sseg * 2;
        bf16x8 h0 = *(bf16x8*)(L + (base ^ c));
        bf16x8 h1 = *(bf16x8*)(L + ((base + 16) ^ c));
        us* o = Xbt + ((size_t)b * DD + d0 + d) * SS + s0 + sseg;
        *(bf16x8*)o       = h0;
        *(bf16x8*)(o + 8) = h1;
    }
}

// ---------------------------------------------------------------------------
// Gt[p][i] = (1/sqrt(D)) * sum_a Wv[a,i] * Wq[a,p]
// ---------------------------------------------------------------------------
__global__ __launch_bounds__(256) void k_prepG(const float* __restrict__ Wv,
        const float* __restrict__ Wq, us* __restrict__ Gt) {
    __shared__ float Sq[32][64], Sv[32][64];
    const int tid = threadIdx.x;
    const int p0 = blockIdx.x * 64, i0 = blockIdx.y * 64;
    const int tp = tid & 15, ti = tid >> 4;
    float acc[4][4] = {};
    for (int a0 = 0; a0 < DD; a0 += 32) {
        #pragma unroll
        for (int j = 0; j < 2; ++j) {
            int slot = tid + j * 256;
            int row = slot >> 4, c4 = (slot & 15) * 4;
            *(f32x4*)&Sq[row][c4] = *(const f32x4*)(Wq + (size_t)(a0 + row) * DD + p0 + c4);
            *(f32x4*)&Sv[row][c4] = *(const f32x4*)(Wv + (size_t)(a0 + row) * DD + i0 + c4);
        }
        __syncthreads();
        for (int a = 0; a < 32; ++a) {
            f32x4 q = *(f32x4*)&Sq[a][tp * 4];
            f32x4 v = *(f32x4*)&Sv[a][ti * 4];
            #pragma unroll
            for (int x = 0; x < 4; ++x)
                #pragma unroll
                for (int y = 0; y < 4; ++y)
                    acc[x][y] += q[x] * v[y];
        }
        __syncthreads();
    }
    const float sc = 0.044194173824159216f;
    #pragma unroll
    for (int x = 0; x < 4; ++x)
        #pragma unroll
        for (int y = 0; y < 4; ++y)
            Gt[(size_t)(p0 + tp * 4 + x) * DD + i0 + ti * 4 + y] = f2b(acc[x][y] * sc);
}

// u[p] = (1/sqrt(D)) * sum_a bv[a] * Wq[a,p]
__global__ __launch_bounds__(512) void k_prepU(const float* __restrict__ Wq,
        const float* __restrict__ bv, float* __restrict__ u) {
    int p = threadIdx.x;
    float s = 0.f;
    for (int a0 = 0; a0 < DD; a0 += 8) {
        #pragma unroll
        for (int j = 0; j < 8; ++j)
            s += bv[a0 + j] * Wq[(size_t)(a0 + j) * DD + p];
    }
    u[p] = s * 0.044194173824159216f;
}

__global__ void k_prepW(const float* __restrict__ Wk, us* __restrict__ Wkb) {
    int i = (blockIdx.x * 256 + threadIdx.x) * 4;
    f32x4 v = *(const f32x4*)(Wk + i);
    us4 o; o.x = f2b(v.x); o.y = f2b(v.y); o.z = f2b(v.z); o.w = f2b(v.w);
    *(us4*)(Wkb + i) = o;
}

// ---------------------------------------------------------------------------
// bf16 GEMM: C[row,n] = sum_k A[row,k]*Bm[n,k] + bias[n]
// ---------------------------------------------------------------------------
template<int OUTMODE>
__global__ __launch_bounds__(256, 2) void k_gemm(
        const us* __restrict__ A, const us* __restrict__ Bm,
        const float* __restrict__ bias, void* __restrict__ outp) {
    __shared__ __align__(16) us As[2][128 * 64];
    __shared__ __align__(16) us Bs[2][128 * 64];
    const int tid = threadIdx.x;
    const int lane = tid & 63;
    const int w = tid >> 6;
    const int wr = w >> 1, wc = w & 1;
    const int l15 = lane & 15, lg = lane >> 4;
    const int b = blockIdx.x >> 4;
    const int s0 = (blockIdx.x & 15) * 128;
    const int n0 = blockIdx.y * 128;
    const char* abase = (const char*)(A + ((size_t)b * SS + s0) * DD);
    const char* bbase = (const char*)Bm + (size_t)n0 * 1024;

    f32x4 acc[4][4];
    #pragma unroll
    for (int m = 0; m < 4; ++m)
        #pragma unroll
        for (int n = 0; n < 4; ++n) acc[m][n] = (f32x4)(0.0f);

    auto stage = [&](int db, int p) {
        #pragma unroll
        for (int j = 0; j < 4; ++j) {
            int x = (tid + j * 256) * 16;
            int gx = x ^ (((x >> 7) & 7) << 4);
            int row = gx >> 7, col = gx & 127;
            gl16(abase + (size_t)row * 1024 + p * 128 + col, (char*)As[db] + x);
            gl16(bbase + (size_t)row * 1024 + p * 128 + col, (char*)Bs[db] + x);
        }
    };

    stage(0, 0);
    for (int p = 0; p < 8; ++p) {
        if (p < 7) { stage((p + 1) & 1, p + 1); WAITV(8); }
        else       { WAITV(0); }
        BAR();
        const us* Ac = As[p & 1]; const us* Bc = Bs[p & 1];
        __builtin_amdgcn_s_setprio(1);
        #pragma unroll
        for (int kk = 0; kk < 2; ++kk) {
            bf16x8 af[4], bfr[4];
            #pragma unroll
            for (int m = 0; m < 4; ++m) af[m]  = ldfrag(Ac, 64 * wr + 16 * m + l15, kk * 32 + 8 * lg, 7);
            #pragma unroll
            for (int n = 0; n < 4; ++n) bfr[n] = ldfrag(Bc, 64 * wc + 16 * n + l15, kk * 32 + 8 * lg, 7);
            #pragma unroll
            for (int m = 0; m < 4; ++m)
                #pragma unroll
                for (int n = 0; n < 4; ++n)
                    acc[m][n] = MFMA16(af[m], bfr[n], acc[m][n]);
        }
        __builtin_amdgcn_s_setprio(0);
        BAR();
    }

    #pragma unroll
    for (int m = 0; m < 4; ++m) {
        #pragma unroll
        for (int n = 0; n < 4; ++n) {
            int col = n0 + 64 * wc + 16 * n + l15;
            float bia = bias[col];
            #pragma unroll
            for (int r = 0; r < 4; ++r) {
                int row = s0 + 64 * wr + 16 * m + 4 * lg + r;
                float v = acc[m][n][r] + bia;
                if (OUTMODE == 0)
                    ((us*)outp)[((size_t)b * SS + row) * DD + col] = f2b(v);
                else
                    ((float*)outp)[((size_t)row * BB + b) * DD + col] = v;
            }
        }
    }
}

// ---------------------------------------------------------------------------
// Flash attention v19 = r11 (v13) with ONE barrier per interval.
//   Ring-4 FIFO argument: interval m reads slot m&3 and (at its END) issues
//   the DMA for chunk m+3 into slot (m+3)&3 = (m-1)&3, which was read in
//   interval m-1; every wave passed BAR(m) only after its interval-(m-1)
//   reads completed (lgkmcnt-drained before MFMA) -> single BAR per interval
//   already separates last-read from next-write.  Barriers/step 17 -> 9.
//   Everything else (geometry, locality, registers, chunk stream, WAITV
//   accounting: 3 chunks outstanding at wait, need oldest -> WAITV(8))
//   identical to the 257 us r11 kernel.
// ---------------------------------------------------------------------------
__global__ __launch_bounds__(512, 2) void k_attn(
        const us* __restrict__ Vtb, const us* __restrict__ Xb,
        const us* __restrict__ Xbt, us* __restrict__ Ob) {
    __shared__ __align__(16) us BUFS[4][16384];  // 4 x 32KB ring
    __shared__ __align__(16) us Pb[64 * 128];    // P [64 r][128 t], 256B rows, swz
    __shared__ float red[2][64];

    const int tid = threadIdx.x;
    const int lane = tid & 63;
    const int w = tid >> 6;
    const int rg = w & 3;          // rows 16*rg .. +15
    const int cg = w >> 2;         // t-half (QK) / e-half-within-quarter (PV)
    const int l15 = lane & 15, lg = lane >> 4;

    // XCD-batch locality (r11): XCD x = wg&7 -> batch 8*(wg>>8)+x
    const int wg = blockIdx.x;
    const int b  = ((wg >> 8) << 3) | (wg & 7);
    const int s0 = ((wg >> 3) & 31) * 64;

    const char* vbase  = (const char*)(Vtb + ((size_t)b * SS + s0) * DD);
    const char* xabase = (const char*)(Xb  + (size_t)b * SS * DD);
    const char* xtbase = (const char*)(Xbt + (size_t)b * DD * SS);

    // chunk c (8/step): i=c&7: i<4 -> X k-quarter i rows t0..t0+127;
    //                   i>=4 -> XT e-quarter (i-4) cols t0..t0+127
    auto issue = [&](int cflat, us* dst0) {
        int c = cflat & 127;
        int i = c & 7, t0 = (c >> 3) << 7;
        char* dst = (char*)dst0;
        if (i < 4) {
            #pragma unroll
            for (int j = 0; j < 4; ++j) {
                int x = tid * 16 + j * 8192;
                int gx = x ^ (((x >> 8) & 15) << 4);
                int row = gx >> 8, col = gx & 255;
                gl16(xabase + (size_t)(t0 + row) * 1024 + i * 256 + col, dst + x);
            }
        } else {
            #pragma unroll
            for (int j = 0; j < 4; ++j) {
                int x = tid * 16 + j * 8192;
                int gx = x ^ (((x >> 8) & 15) << 4);
                int row = gx >> 8, col = gx & 255;
                gl16(xtbase + (size_t)((i - 4) * 128 + row) * (SS * 2)
                            + (size_t)t0 * 2 + col, dst + x);
            }
        }
    };

    // ---- prologue: Vt tile (64 rows x 512 k) -> af regs via 4x16KB subs ----
    #pragma unroll
    for (int p = 0; p < 4; ++p) {
        #pragma unroll
        for (int j = 0; j < 2; ++j) {
            int x = tid * 16 + j * 8192;
            int gx = x ^ (((x >> 8) & 15) << 4);
            int row = gx >> 8, col = gx & 255;
            gl16(vbase + (size_t)row * 1024 + p * 256 + col,
                 (char*)BUFS[0] + p * 16384 + x);
        }
    }
    WAITV(0); BAR();
    bf16x8 af[16];
    #pragma unroll
    for (int p = 0; p < 4; ++p)
        #pragma unroll
        for (int kk = 0; kk < 4; ++kk)
            af[4 * p + kk] = ldfrag8((const us*)BUFS[0] + p * 8192,
                                     16 * rg + l15, 32 * kk + 8 * lg);
    WAITL(); BAR();

    issue(0, BUFS[0]);
    issue(1, BUFS[1]);
    issue(2, BUFS[2]);

    f32x4 accv[4][4];
    #pragma unroll
    for (int ph = 0; ph < 4; ++ph)
        #pragma unroll
        for (int nt = 0; nt < 4; ++nt) accv[ph][nt] = (f32x4)(0.0f);
    float lsum[4] = {0.f, 0.f, 0.f, 0.f};
    const int idx = 16 * rg + 4 * lg;

    for (int step = 0; step < 16; ++step) {
        const int cbase = step * 8;
        f32x4 sacc[4];
        #pragma unroll
        for (int nt = 0; nt < 4; ++nt) sacc[nt] = (f32x4)(0.0f);

        // -------- QK: 4 single-barrier intervals (k-quarters) --------
        #pragma unroll
        for (int p = 0; p < 4; ++p) {
            const int c = cbase + p;
            WAITV(8); BAR();
            const us* sl = BUFS[c & 3];
            __builtin_amdgcn_s_setprio(1);
            #pragma unroll
            for (int kk = 0; kk < 4; ++kk)
                #pragma unroll
                for (int nt = 0; nt < 4; ++nt) {
                    bf16x8 bq = ldfrag8(sl, 64 * cg + 16 * nt + l15, 32 * kk + 8 * lg);
                    sacc[nt] = MFMA16(af[4 * p + kk], bq, sacc[nt]);
                }
            __builtin_amdgcn_s_setprio(0);
            issue(c + 3, BUFS[(c + 3) & 3]);
        }

        // -------- softmax (static max): P = exp(s) --------
        #pragma unroll
        for (int nt = 0; nt < 4; ++nt)
            #pragma unroll
            for (int ri = 0; ri < 4; ++ri)
                sacc[nt][ri] = __expf(sacc[nt][ri]);
        #pragma unroll
        for (int nt = 0; nt < 4; ++nt)
            #pragma unroll
            for (int ri = 0; ri < 4; ++ri) {
                int row = idx + ri;
                int col = 64 * cg + 16 * nt + l15;
                int off = ((row << 8) + (col << 1)) ^ ((row & 15) << 4);
                *(us*)((char*)Pb + off) = f2b(sacc[nt][ri]);
            }
        #pragma unroll
        for (int ri = 0; ri < 4; ++ri) {
            float s = sacc[0][ri] + sacc[1][ri] + sacc[2][ri] + sacc[3][ri];
            s += __shfl_xor(s, 1); s += __shfl_xor(s, 2);
            s += __shfl_xor(s, 4); s += __shfl_xor(s, 8);
            lsum[ri] += s;
        }
        WAITL(); BAR();
        bf16x8 pa[4];
        #pragma unroll
        for (int kk = 0; kk < 4; ++kk)
            pa[kk] = ldfrag8(Pb, 16 * rg + l15, 32 * kk + 8 * lg);

        // -------- PV: 4 single-barrier intervals (e-quarters) --------
        #pragma unroll
        for (int p = 0; p < 4; ++p) {
            const int c = cbase + 4 + p;
            WAITV(8); BAR();
            const us* sl = BUFS[c & 3];
            __builtin_amdgcn_s_setprio(1);
            #pragma unroll
            for (int kk = 0; kk < 4; ++kk)
                #pragma unroll
                for (int nt = 0; nt < 4; ++nt) {
                    bf16x8 bx = ldfrag8(sl, 64 * cg + 16 * nt + l15, 32 * kk + 8 * lg);
                    accv[p][nt] = MFMA16(pa[kk], bx, accv[p][nt]);
                }
            __builtin_amdgcn_s_setprio(0);
            issue(c + 3, BUFS[(c + 3) & 3]);
        }
    }

    WAITV(0);
    // -------- epilogue: cross-cg sum, O' = acc / tot --------
    if (l15 == 0) {
        #pragma unroll
        for (int ri = 0; ri < 4; ++ri)
            red[cg][idx + ri] = lsum[ri];
    }
    WAITL(); BAR();
    float tot[4];
    #pragma unroll
    for (int ri = 0; ri < 4; ++ri)
        tot[ri] = red[0][idx + ri] + red[1][idx + ri];
    us* orow = Ob + ((size_t)b * SS + s0) * DD;
    #pragma unroll
    for (int ph = 0; ph < 4; ++ph)
        #pragma unroll
        for (int nt = 0; nt < 4; ++nt)
            #pragma unroll
            for (int ri = 0; ri < 4; ++ri) {
                int row = idx + ri;
                int e = 128 * ph + 64 * cg + 16 * nt + l15;
                orow[(size_t)row * DD + e] = f2b(accv[ph][nt][ri] / tot[ri]);
            }
}

extern "C" void kernel_launch(void* const* d_in, const int* in_sizes, int n_in,
                              void* d_out, int out_size, void* d_ws, size_t ws_size,
                              hipStream_t stream) {
    const float* seq = (const float*)d_in[0];
    const float* Wv  = (const float*)d_in[1];
    const float* bv  = (const float*)d_in[2];
    const float* Wq  = (const float*)d_in[3];
    // d_in[4] = bq: softmax-row-constant -> unused
    const float* Wk  = (const float*)d_in[5];
    const float* bk  = (const float*)d_in[6];

    char* ws = (char*)d_ws;
    us*    Xb  = (us*)ws;                                  // [B][S][D] bf16, 32MB
    us*    Xbt = (us*)(ws + (size_t)33554432);             // [B][D][S] bf16, 32MB
    us*    Vtb = (us*)(ws + (size_t)67108864);             // [B][S][D] bf16, 32MB (reused as O')
    us*    Gt  = (us*)(ws + (size_t)100663296);            // [D][D] bf16
    us*    Wkb = (us*)(ws + (size_t)101187584);            // [D][D] bf16
    float* u   = (float*)(ws + (size_t)101711872);         // [D] fp32

    k_prep_x<<<dim3(8, 32, 16), 256, 0, stream>>>(seq, Xb, Xbt);
    k_prepG<<<dim3(8, 8), 256, 0, stream>>>(Wv, Wq, Gt);
    k_prepU<<<1, 512, 0, stream>>>(Wq, bv, u);
    k_prepW<<<256, 256, 0, stream>>>(Wk, Wkb);

    k_gemm<0><<<dim3(256, 4), 256, 0, stream>>>(Xb, Gt, u, (void*)Vtb);   // Vt = X*G + u
    k_attn<<<512, 512, 0, stream>>>(Vtb, Xb, Xbt, Vtb);                   // O' over Vt
    k_gemm<1><<<dim3(256, 4), 256, 0, stream>>>(Vtb, Wkb, bk, d_out);     // out = O'*Wk^T + bk
}